// Round 7
// baseline (530.463 us; speedup 1.0000x reference)
//
#include <hip/hip_runtime.h>
#include <hip/hip_bf16.h>

// MHA: B=4 T=2048 C=1024 H=16 D=64, fp32 in/out, bf16 MFMA internally.
// R7: attention rounds doubled to kv=128 (two proven-conflict-free 64-kv
//     halves per barrier pair -> barrier drains halved), V fragments hoisted
//     to registers per half (LDS reads halved), launch_bounds(256,4) so all
//     4 LDS-resident blocks fit (40 KB/block). GEMMs unchanged from R6.

typedef unsigned short u16;
typedef __bf16 bf16_t;
typedef bf16_t bf16x8 __attribute__((ext_vector_type(8)));
typedef float f32x4 __attribute__((ext_vector_type(4)));
typedef u16 u16x8 __attribute__((ext_vector_type(8)));
typedef const __attribute__((address_space(1))) void* as1cv;
typedef __attribute__((address_space(3))) void* as3v;

#define BB 4
#define TT 2048
#define CC 1024
#define HH 16
#define DD 64

static __device__ __forceinline__ u16 f2bf(float f) {
  union { float f; unsigned int u; } x; x.f = f;
  unsigned int u = x.u;
  u += 0x7fff + ((u >> 16) & 1);   // round-to-nearest-even
  return (u16)(u >> 16);
}

// pack two f32 -> two bf16 (truncation) in one v_perm_b32
static __device__ __forceinline__ unsigned int pack2(float lo, float hi) {
  return __builtin_amdgcn_perm(__float_as_uint(hi), __float_as_uint(lo),
                               0x07060302u);
}

// ---------------- fp32 -> bf16 row cast (x) --------------------------------
__global__ __launch_bounds__(256) void cast_f32_bf16(
    const float* __restrict__ in, u16* __restrict__ out) {
  int i = (blockIdx.x * 256 + threadIdx.x) * 4;
  float4 v = *(const float4*)(in + i);
  ushort4 o;
  o.x = f2bf(v.x); o.y = f2bf(v.y); o.z = f2bf(v.z); o.w = f2bf(v.w);
  *(ushort4*)(out + i) = o;
}

// ---------------- transpose + cast fp32[K][N] -> bf16[N][K] ----------------
__global__ __launch_bounds__(256) void transpose_cast(
    const float* __restrict__ in, u16* __restrict__ out, int K, int N) {
  __shared__ float tile[32][33];
  int n0 = blockIdx.x * 32, k0 = blockIdx.y * 32;
  int tx = threadIdx.x & 31, ty = threadIdx.x >> 5;  // 32 x 8
#pragma unroll
  for (int i = 0; i < 32; i += 8)
    tile[ty + i][tx] = in[(size_t)(k0 + ty + i) * N + n0 + tx];
  __syncthreads();
#pragma unroll
  for (int i = 0; i < 32; i += 8)
    out[(size_t)(n0 + ty + i) * K + k0 + tx] = f2bf(tile[tx][ty + i]);
}

// ---------------- GEMM: C[M][N] = A[M][K](bf16) * Bt[N][K]^T + bias --------
// BK=64: per round 8 global_load_lds + 2 sub-steps of (8 ds_read_b128 +
// 16 MFMA). LDS phys 16B slot = logical blk ^ (row & 7).
__global__ __launch_bounds__(256) void gemm_bt(
    const u16* __restrict__ A, const u16* __restrict__ Bt,
    const float* __restrict__ bias,
    int M, int N, int K, int mode,
    u16* __restrict__ qb, u16* __restrict__ kb, u16* __restrict__ vt,
    float* __restrict__ outf) {
  __shared__ u16 As[128][64];   // 16 KB
  __shared__ u16 Bs[128][64];   // 16 KB
  const int tid = threadIdx.x;
  const int lane = tid & 63, wave = tid >> 6;
  const int quad = lane >> 4, l16 = lane & 15;
  const int wy = wave >> 1, wx = wave & 1;  // 2x2 waves, 64x64 each
  const int m0 = blockIdx.x * 128, n0 = blockIdx.y * 128;
  const int srow = lane >> 3, sblk = (lane & 7) ^ (lane >> 3);  // row&7==srow
  const int rsw = l16 & 7;  // read-side swizzle

  f32x4 acc[4][4] = {};

  for (int k0 = 0; k0 < K; k0 += 64) {
#pragma unroll
    for (int i = 0; i < 4; i++) {
      int lr = wave * 32 + i * 8;          // lds row base (mult of 8)
      int row = lr + srow;
      __builtin_amdgcn_global_load_lds(
          (as1cv)(A + (size_t)(m0 + row) * K + k0 + sblk * 8),
          (as3v)(&As[lr][0]), 16, 0, 0);
      __builtin_amdgcn_global_load_lds(
          (as1cv)(Bt + (size_t)(n0 + row) * K + k0 + sblk * 8),
          (as3v)(&Bs[lr][0]), 16, 0, 0);
    }
    __syncthreads();
#pragma unroll
    for (int ks = 0; ks < 2; ks++) {
      const int pcol = ((ks * 4 + quad) ^ rsw) * 8;
      bf16x8 af[4], bfr[4];
#pragma unroll
      for (int i = 0; i < 4; i++)
        af[i] = *(const bf16x8*)&As[wy * 64 + i * 16 + l16][pcol];
#pragma unroll
      for (int j = 0; j < 4; j++)
        bfr[j] = *(const bf16x8*)&Bs[wx * 64 + j * 16 + l16][pcol];
#pragma unroll
      for (int i = 0; i < 4; i++)
#pragma unroll
        for (int j = 0; j < 4; j++)
          acc[i][j] = __builtin_amdgcn_mfma_f32_16x16x32_bf16(af[i], bfr[j], acc[i][j], 0, 0, 0);
    }
    __syncthreads();
  }

  // epilogue: C/D layout col=lane&15, row=quad*4+reg. Branch is block-uniform.
  if (mode == 1) {
#pragma unroll
    for (int i = 0; i < 4; i++)
#pragma unroll
      for (int j = 0; j < 4; j++) {
        int nn = n0 + wx * 64 + j * 16 + l16;
        float bv = bias[nn];
#pragma unroll
        for (int r = 0; r < 4; r++) {
          int mm = m0 + wy * 64 + i * 16 + quad * 4 + r;
          outf[(size_t)mm * N + nn] = acc[i][j][r] + bv;
        }
      }
  } else {
    const int b = m0 >> 11;                       // batch (block-uniform)
    const int tb = (m0 & 2047) + wy * 64 + quad * 4;
    if (n0 < 1024) {        // ---- Q, pre-scaled by 1/sqrt(d)*log2(e) ----
#pragma unroll
      for (int j = 0; j < 4; j++) {
        int nn = n0 + wx * 64 + j * 16 + l16;
        int h = nn >> 6, dd = nn & 63;
        float bv = bias[nn];
        u16* base = qb + ((size_t)(b * HH + h) * TT) * DD + dd;
#pragma unroll
        for (int i = 0; i < 4; i++)
#pragma unroll
          for (int r = 0; r < 4; r++)
            base[(size_t)(tb + i * 16 + r) * DD] =
                f2bf((acc[i][j][r] + bv) * 0.1803368801111f);
      }
    } else if (n0 < 2048) { // ---- K ----
#pragma unroll
      for (int j = 0; j < 4; j++) {
        int nn = n0 + wx * 64 + j * 16 + l16;
        int rem = nn & 1023, h = rem >> 6, dd = rem & 63;
        float bv = bias[nn];
        u16* base = kb + ((size_t)(b * HH + h) * TT) * DD + dd;
#pragma unroll
        for (int i = 0; i < 4; i++)
#pragma unroll
          for (int r = 0; r < 4; r++)
            base[(size_t)(tb + i * 16 + r) * DD] = f2bf(acc[i][j][r] + bv);
      }
    } else {                // ---- V, stored transposed [B,H,D,T] ----
#pragma unroll
      for (int j = 0; j < 4; j++) {
        int nn = n0 + wx * 64 + j * 16 + l16;
        int rem = nn & 1023, h = rem >> 6, dd = rem & 63;
        float bv = bias[nn];
        u16* base = vt + ((size_t)(b * HH + h) * DD + dd) * TT;
#pragma unroll
        for (int i = 0; i < 4; i++)
#pragma unroll
          for (int r = 0; r < 4; r++)
            base[tb + i * 16 + r] = f2bf(acc[i][j][r] + bv);
      }
    }
  }
}

// ---------------- flash attention (block-cooperative, S^T/O^T) -------------
// grid (bh=64, tile=16); block = 4 waves = 128 q rows. kv rounds of 128 =
// two proven 64-kv halves per barrier pair. Linear block id === bh (mod 8)
// -> per-bh XCD L2 locality.
__global__ __launch_bounds__(256, 4) void attn_kernel(
    const u16* __restrict__ q_buf, const u16* __restrict__ k_buf,
    const u16* __restrict__ v_t, u16* __restrict__ attn_out) {
  __shared__ __align__(16) u16 Ks[2][64][64];   // K  [kv][d]   16 KB
  __shared__ __align__(16) u16 Vs[2][64][64];   // V^T [d][kv]  16 KB
  __shared__ __align__(16) u16 Pl[4][16][64];   // per-wave P [q][kv] 8 KB
  const int tid = threadIdx.x;
  const int lane = tid & 63, wave = tid >> 6;
  const int quad = lane >> 4, l16 = lane & 15;
  const int bh = blockIdx.x;
  const int b = bh >> 4, h = bh & 15;
  const int tile = 15 - (int)blockIdx.y;        // heavy tiles dispatch first
  const int qt0 = tile * 128;
  const int qw = qt0 + wave * 32;               // wave's first q row
  const u16* Q = q_buf + (size_t)bh * TT * DD;
  const u16* Kp = k_buf + (size_t)bh * TT * DD;
  const u16* Vt = v_t + (size_t)bh * DD * TT;

  // staging geometry: lane -> (row group l>>3, 16B blk (l&7)^(l>>3))
  const int srow = lane >> 3;
  const int sblk = (lane & 7) ^ srow;
  const int swz = l16 & 7;                      // fragment-read swizzle

  bf16x8 qf[2][2];
#pragma unroll
  for (int f = 0; f < 2; f++)
#pragma unroll
    for (int h2 = 0; h2 < 2; h2++)
      qf[f][h2] = *(const bf16x8*)(Q + (size_t)(qw + f * 16 + l16) * DD + h2 * 32 + quad * 8);

  f32x4 o[2][4] = {};   // O^T[d = g*16+quad*4+r][q = l16]
  float l_p[2] = {0.f, 0.f};

  const int my_end = qw + 32;
  const int kv_stop = qt0 + 128;
  for (int kv0 = 0; kv0 < kv_stop; kv0 += 128) {
    // ---- stage both 64-kv halves: K rows and V^T cols ----
#pragma unroll
    for (int hh = 0; hh < 2; hh++)
#pragma unroll
      for (int i = 0; i < 2; i++) {
        int r = wave * 16 + i * 8 + srow;       // lds row 0..63 (row&7==srow)
        __builtin_amdgcn_global_load_lds(
            (as1cv)(Kp + (size_t)(kv0 + hh * 64 + r) * DD + sblk * 8),
            (as3v)(&Ks[hh][wave * 16 + i * 8][0]), 16, 0, 0);
        __builtin_amdgcn_global_load_lds(
            (as1cv)(Vt + (size_t)r * TT + kv0 + hh * 64 + sblk * 8),
            (as3v)(&Vs[hh][wave * 16 + i * 8][0]), 16, 0, 0);
      }
    __syncthreads();

#pragma unroll
    for (int hh = 0; hh < 2; hh++) {
      const int kb0 = kv0 + hh * 64;
      if (kb0 < my_end) {                       // wave-uniform causal skip
        const bool edge = (kb0 + 63 > qw);
        // ---- S^T = K * Q^T ----
        f32x4 s[2][4] = {};
#pragma unroll
        for (int kg = 0; kg < 4; kg++) {
          bf16x8 ka = *(const bf16x8*)&Ks[hh][kg * 16 + l16][(quad ^ swz) * 8];
          bf16x8 kb2 = *(const bf16x8*)&Ks[hh][kg * 16 + l16][((4 + quad) ^ swz) * 8];
#pragma unroll
          for (int f = 0; f < 2; f++) {
            s[f][kg] = __builtin_amdgcn_mfma_f32_16x16x32_bf16(ka, qf[f][0], s[f][kg], 0, 0, 0);
            s[f][kg] = __builtin_amdgcn_mfma_f32_16x16x32_bf16(kb2, qf[f][1], s[f][kg], 0, 0, 0);
          }
        }
        // ---- V fragments hoisted (shared across both f) ----
        bf16x8 vf[4][2];
#pragma unroll
        for (int g = 0; g < 4; g++)
#pragma unroll
          for (int c = 0; c < 2; c++)
            vf[g][c] = *(const bf16x8*)&Vs[hh][g * 16 + l16][((c * 4 + quad) ^ swz) * 8];
        // ---- softmax (fixed-max exp2) + P store + PV ----
#pragma unroll
        for (int f = 0; f < 2; f++) {
          const int qi = qw + f * 16 + l16;
#pragma unroll
          for (int kg = 0; kg < 4; kg++) {
            float v0 = s[f][kg][0], v1 = s[f][kg][1], v2 = s[f][kg][2], v3 = s[f][kg][3];
            if (edge) {
              int kvb = kb0 + kg * 16 + quad * 4;
              v0 = (kvb + 0 <= qi) ? v0 : -1e30f;
              v1 = (kvb + 1 <= qi) ? v1 : -1e30f;
              v2 = (kvb + 2 <= qi) ? v2 : -1e30f;
              v3 = (kvb + 3 <= qi) ? v3 : -1e30f;
            }
            float e0 = __builtin_amdgcn_exp2f(v0);
            float e1 = __builtin_amdgcn_exp2f(v1);
            float e2 = __builtin_amdgcn_exp2f(v2);
            float e3 = __builtin_amdgcn_exp2f(v3);
            l_p[f] += (e0 + e1) + (e2 + e3);
            uint2 pk;
            pk.x = pack2(e0, e1);
            pk.y = pack2(e2, e3);
            // P[q=l16][kv]: 16B blk = kg*2+(quad>>1), swizzled; 8B half = quad&1
            *(uint2*)&Pl[wave][l16][((kg * 2 + (quad >> 1)) ^ swz) * 8 + (quad & 1) * 4] = pk;
          }
          __threadfence_block();                // same-wave DS write->read order
#pragma unroll
          for (int c = 0; c < 2; c++) {
            bf16x8 pa = *(const bf16x8*)&Pl[wave][l16][((c * 4 + quad) ^ swz) * 8];
#pragma unroll
            for (int g = 0; g < 4; g++)
              o[f][g] = __builtin_amdgcn_mfma_f32_16x16x32_bf16(vf[g][c], pa, o[f][g], 0, 0, 0);
          }
        }
      }
    }
    __syncthreads();
  }

  // epilogue: reduce l across quads, scale, vectorized store
#pragma unroll
  for (int f = 0; f < 2; f++) {
    float l = l_p[f];
    l += __shfl_xor(l, 16);
    l += __shfl_xor(l, 32);
    float inv_l = 1.0f / l;
    int trow = qw + f * 16 + l16;
#pragma unroll
    for (int g = 0; g < 4; g++) {
      ushort4 st;
      st.x = f2bf(o[f][g][0] * inv_l);
      st.y = f2bf(o[f][g][1] * inv_l);
      st.z = f2bf(o[f][g][2] * inv_l);
      st.w = f2bf(o[f][g][3] * inv_l);
      *(ushort4*)(attn_out + ((size_t)(b * TT + trow)) * CC + h * DD + g * 16 + quad * 4) = st;
    }
  }
}

extern "C" void kernel_launch(void* const* d_in, const int* in_sizes, int n_in,
                              void* d_out, int out_size, void* d_ws, size_t ws_size,
                              hipStream_t stream) {
  const float* x = (const float*)d_in[0];
  const float* w_qkv = (const float*)d_in[1];
  const float* b_qkv = (const float*)d_in[2];
  const float* w_proj = (const float*)d_in[3];
  const float* b_proj = (const float*)d_in[4];
  float* out = (float*)d_out;
  char* ws = (char*)d_ws;

  // workspace layout (72 MB total); xb aliases ao (xb dead before attn runs)
  u16* wqkvT = (u16*)(ws);                    // 3072*1024*2 = 6291456
  u16* wprojT = (u16*)(ws + 6291456);         // 1024*1024*2 = 2097152
  u16* qb = (u16*)(ws + 8388608);             // [B,H,T,D] bf16, 16 MB
  u16* kb = (u16*)(ws + 25165824);            // [B,H,T,D] bf16, 16 MB
  u16* vt = (u16*)(ws + 41943040);            // [B,H,D,T] bf16, 16 MB
  u16* ao = (u16*)(ws + 58720256);            // [B,T,C]   bf16, 16 MB
  u16* xb = ao;                               // x cast to bf16 (aliased)

  cast_f32_bf16<<<dim3(8192), 256, 0, stream>>>(x, xb);
  transpose_cast<<<dim3(96, 32), 256, 0, stream>>>(w_qkv, wqkvT, 1024, 3072);
  transpose_cast<<<dim3(32, 32), 256, 0, stream>>>(w_proj, wprojT, 1024, 1024);
  gemm_bt<<<dim3(64, 24), 256, 0, stream>>>(xb, wqkvT, b_qkv, 8192, 3072, 1024, 0,
                                            qb, kb, vt, nullptr);
  attn_kernel<<<dim3(64, 16), 256, 0, stream>>>(qb, kb, vt, ao);
  gemm_bt<<<dim3(64, 8), 256, 0, stream>>>(ao, wprojT, b_proj, 8192, 1024, 1024, 1,
                                           nullptr, nullptr, nullptr, out);
}

// Round 8
// 240.591 us; speedup vs baseline: 2.2048x; 2.2048x over previous
//
#include <hip/hip_runtime.h>
#include <hip/hip_bf16.h>

// MHA: B=4 T=2048 C=1024 H=16 D=64, fp32 in/out, bf16 MFMA internally.
// R8: R7 post-mortem — launch_bounds(256,4) + hoisted V frags caused VGPR
//     spill (603 MB scratch writes). Fix: keep kv=128 double-staged rounds
//     (half the barrier drains vs R6) but read V per-c from LDS (no hoist)
//     and return to launch_bounds(256,3) (R6's proven no-spill config).
//     GEMMs unchanged from R6.

typedef unsigned short u16;
typedef __bf16 bf16_t;
typedef bf16_t bf16x8 __attribute__((ext_vector_type(8)));
typedef float f32x4 __attribute__((ext_vector_type(4)));
typedef u16 u16x8 __attribute__((ext_vector_type(8)));
typedef const __attribute__((address_space(1))) void* as1cv;
typedef __attribute__((address_space(3))) void* as3v;

#define BB 4
#define TT 2048
#define CC 1024
#define HH 16
#define DD 64

static __device__ __forceinline__ u16 f2bf(float f) {
  union { float f; unsigned int u; } x; x.f = f;
  unsigned int u = x.u;
  u += 0x7fff + ((u >> 16) & 1);   // round-to-nearest-even
  return (u16)(u >> 16);
}

// pack two f32 -> two bf16 (truncation) in one v_perm_b32
static __device__ __forceinline__ unsigned int pack2(float lo, float hi) {
  return __builtin_amdgcn_perm(__float_as_uint(hi), __float_as_uint(lo),
                               0x07060302u);
}

// ---------------- fp32 -> bf16 row cast (x) --------------------------------
__global__ __launch_bounds__(256) void cast_f32_bf16(
    const float* __restrict__ in, u16* __restrict__ out) {
  int i = (blockIdx.x * 256 + threadIdx.x) * 4;
  float4 v = *(const float4*)(in + i);
  ushort4 o;
  o.x = f2bf(v.x); o.y = f2bf(v.y); o.z = f2bf(v.z); o.w = f2bf(v.w);
  *(ushort4*)(out + i) = o;
}

// ---------------- transpose + cast fp32[K][N] -> bf16[N][K] ----------------
__global__ __launch_bounds__(256) void transpose_cast(
    const float* __restrict__ in, u16* __restrict__ out, int K, int N) {
  __shared__ float tile[32][33];
  int n0 = blockIdx.x * 32, k0 = blockIdx.y * 32;
  int tx = threadIdx.x & 31, ty = threadIdx.x >> 5;  // 32 x 8
#pragma unroll
  for (int i = 0; i < 32; i += 8)
    tile[ty + i][tx] = in[(size_t)(k0 + ty + i) * N + n0 + tx];
  __syncthreads();
#pragma unroll
  for (int i = 0; i < 32; i += 8)
    out[(size_t)(n0 + ty + i) * K + k0 + tx] = f2bf(tile[tx][ty + i]);
}

// ---------------- GEMM: C[M][N] = A[M][K](bf16) * Bt[N][K]^T + bias --------
// BK=64: per round 8 global_load_lds + 2 sub-steps of (8 ds_read_b128 +
// 16 MFMA). LDS phys 16B slot = logical blk ^ (row & 7).
__global__ __launch_bounds__(256) void gemm_bt(
    const u16* __restrict__ A, const u16* __restrict__ Bt,
    const float* __restrict__ bias,
    int M, int N, int K, int mode,
    u16* __restrict__ qb, u16* __restrict__ kb, u16* __restrict__ vt,
    float* __restrict__ outf) {
  __shared__ u16 As[128][64];   // 16 KB
  __shared__ u16 Bs[128][64];   // 16 KB
  const int tid = threadIdx.x;
  const int lane = tid & 63, wave = tid >> 6;
  const int quad = lane >> 4, l16 = lane & 15;
  const int wy = wave >> 1, wx = wave & 1;  // 2x2 waves, 64x64 each
  const int m0 = blockIdx.x * 128, n0 = blockIdx.y * 128;
  const int srow = lane >> 3, sblk = (lane & 7) ^ (lane >> 3);  // row&7==srow
  const int rsw = l16 & 7;  // read-side swizzle

  f32x4 acc[4][4] = {};

  for (int k0 = 0; k0 < K; k0 += 64) {
#pragma unroll
    for (int i = 0; i < 4; i++) {
      int lr = wave * 32 + i * 8;          // lds row base (mult of 8)
      int row = lr + srow;
      __builtin_amdgcn_global_load_lds(
          (as1cv)(A + (size_t)(m0 + row) * K + k0 + sblk * 8),
          (as3v)(&As[lr][0]), 16, 0, 0);
      __builtin_amdgcn_global_load_lds(
          (as1cv)(Bt + (size_t)(n0 + row) * K + k0 + sblk * 8),
          (as3v)(&Bs[lr][0]), 16, 0, 0);
    }
    __syncthreads();
#pragma unroll
    for (int ks = 0; ks < 2; ks++) {
      const int pcol = ((ks * 4 + quad) ^ rsw) * 8;
      bf16x8 af[4], bfr[4];
#pragma unroll
      for (int i = 0; i < 4; i++)
        af[i] = *(const bf16x8*)&As[wy * 64 + i * 16 + l16][pcol];
#pragma unroll
      for (int j = 0; j < 4; j++)
        bfr[j] = *(const bf16x8*)&Bs[wx * 64 + j * 16 + l16][pcol];
#pragma unroll
      for (int i = 0; i < 4; i++)
#pragma unroll
        for (int j = 0; j < 4; j++)
          acc[i][j] = __builtin_amdgcn_mfma_f32_16x16x32_bf16(af[i], bfr[j], acc[i][j], 0, 0, 0);
    }
    __syncthreads();
  }

  // epilogue: C/D layout col=lane&15, row=quad*4+reg. Branch is block-uniform.
  if (mode == 1) {
#pragma unroll
    for (int i = 0; i < 4; i++)
#pragma unroll
      for (int j = 0; j < 4; j++) {
        int nn = n0 + wx * 64 + j * 16 + l16;
        float bv = bias[nn];
#pragma unroll
        for (int r = 0; r < 4; r++) {
          int mm = m0 + wy * 64 + i * 16 + quad * 4 + r;
          outf[(size_t)mm * N + nn] = acc[i][j][r] + bv;
        }
      }
  } else {
    const int b = m0 >> 11;                       // batch (block-uniform)
    const int tb = (m0 & 2047) + wy * 64 + quad * 4;
    if (n0 < 1024) {        // ---- Q, pre-scaled by 1/sqrt(d)*log2(e) ----
#pragma unroll
      for (int j = 0; j < 4; j++) {
        int nn = n0 + wx * 64 + j * 16 + l16;
        int h = nn >> 6, dd = nn & 63;
        float bv = bias[nn];
        u16* base = qb + ((size_t)(b * HH + h) * TT) * DD + dd;
#pragma unroll
        for (int i = 0; i < 4; i++)
#pragma unroll
          for (int r = 0; r < 4; r++)
            base[(size_t)(tb + i * 16 + r) * DD] =
                f2bf((acc[i][j][r] + bv) * 0.1803368801111f);
      }
    } else if (n0 < 2048) { // ---- K ----
#pragma unroll
      for (int j = 0; j < 4; j++) {
        int nn = n0 + wx * 64 + j * 16 + l16;
        int rem = nn & 1023, h = rem >> 6, dd = rem & 63;
        float bv = bias[nn];
        u16* base = kb + ((size_t)(b * HH + h) * TT) * DD + dd;
#pragma unroll
        for (int i = 0; i < 4; i++)
#pragma unroll
          for (int r = 0; r < 4; r++)
            base[(size_t)(tb + i * 16 + r) * DD] = f2bf(acc[i][j][r] + bv);
      }
    } else {                // ---- V, stored transposed [B,H,D,T] ----
#pragma unroll
      for (int j = 0; j < 4; j++) {
        int nn = n0 + wx * 64 + j * 16 + l16;
        int rem = nn & 1023, h = rem >> 6, dd = rem & 63;
        float bv = bias[nn];
        u16* base = vt + ((size_t)(b * HH + h) * DD + dd) * TT;
#pragma unroll
        for (int i = 0; i < 4; i++)
#pragma unroll
          for (int r = 0; r < 4; r++)
            base[tb + i * 16 + r] = f2bf(acc[i][j][r] + bv);
      }
    }
  }
}

// ---------------- flash attention (block-cooperative, S^T/O^T) -------------
// grid (bh=64, tile=16); block = 4 waves = 128 q rows. kv rounds of 128 =
// two proven 64-kv halves per barrier pair; V read per-c from LDS (no
// register hoist -> no spill). Linear block id === bh (mod 8) -> XCD L2.
__global__ __launch_bounds__(256, 3) void attn_kernel(
    const u16* __restrict__ q_buf, const u16* __restrict__ k_buf,
    const u16* __restrict__ v_t, u16* __restrict__ attn_out) {
  __shared__ __align__(16) u16 Ks[2][64][64];   // K  [kv][d]   16 KB
  __shared__ __align__(16) u16 Vs[2][64][64];   // V^T [d][kv]  16 KB
  __shared__ __align__(16) u16 Pl[4][16][64];   // per-wave P [q][kv] 8 KB
  const int tid = threadIdx.x;
  const int lane = tid & 63, wave = tid >> 6;
  const int quad = lane >> 4, l16 = lane & 15;
  const int bh = blockIdx.x;
  const int b = bh >> 4, h = bh & 15;
  const int tile = 15 - (int)blockIdx.y;        // heavy tiles dispatch first
  const int qt0 = tile * 128;
  const int qw = qt0 + wave * 32;               // wave's first q row
  const u16* Q = q_buf + (size_t)bh * TT * DD;
  const u16* Kp = k_buf + (size_t)bh * TT * DD;
  const u16* Vt = v_t + (size_t)bh * DD * TT;

  // staging geometry: lane -> (row group l>>3, 16B blk (l&7)^(l>>3))
  const int srow = lane >> 3;
  const int sblk = (lane & 7) ^ srow;
  const int swz = l16 & 7;                      // fragment-read swizzle

  bf16x8 qf[2][2];
#pragma unroll
  for (int f = 0; f < 2; f++)
#pragma unroll
    for (int h2 = 0; h2 < 2; h2++)
      qf[f][h2] = *(const bf16x8*)(Q + (size_t)(qw + f * 16 + l16) * DD + h2 * 32 + quad * 8);

  f32x4 o[2][4] = {};   // O^T[d = g*16+quad*4+r][q = l16]
  float l_p[2] = {0.f, 0.f};

  const int my_end = qw + 32;
  const int kv_stop = qt0 + 128;
  for (int kv0 = 0; kv0 < kv_stop; kv0 += 128) {
    // ---- stage both 64-kv halves: K rows and V^T cols ----
#pragma unroll
    for (int hh = 0; hh < 2; hh++)
#pragma unroll
      for (int i = 0; i < 2; i++) {
        int r = wave * 16 + i * 8 + srow;       // lds row 0..63 (row&7==srow)
        __builtin_amdgcn_global_load_lds(
            (as1cv)(Kp + (size_t)(kv0 + hh * 64 + r) * DD + sblk * 8),
            (as3v)(&Ks[hh][wave * 16 + i * 8][0]), 16, 0, 0);
        __builtin_amdgcn_global_load_lds(
            (as1cv)(Vt + (size_t)r * TT + kv0 + hh * 64 + sblk * 8),
            (as3v)(&Vs[hh][wave * 16 + i * 8][0]), 16, 0, 0);
      }
    __syncthreads();

#pragma unroll
    for (int hh = 0; hh < 2; hh++) {
      const int kb0 = kv0 + hh * 64;
      if (kb0 < my_end) {                       // wave-uniform causal skip
        const bool edge = (kb0 + 63 > qw);
        // ---- S^T = K * Q^T ----
        f32x4 s[2][4] = {};
#pragma unroll
        for (int kg = 0; kg < 4; kg++) {
          bf16x8 ka = *(const bf16x8*)&Ks[hh][kg * 16 + l16][(quad ^ swz) * 8];
          bf16x8 kb2 = *(const bf16x8*)&Ks[hh][kg * 16 + l16][((4 + quad) ^ swz) * 8];
#pragma unroll
          for (int f = 0; f < 2; f++) {
            s[f][kg] = __builtin_amdgcn_mfma_f32_16x16x32_bf16(ka, qf[f][0], s[f][kg], 0, 0, 0);
            s[f][kg] = __builtin_amdgcn_mfma_f32_16x16x32_bf16(kb2, qf[f][1], s[f][kg], 0, 0, 0);
          }
        }
        // ---- softmax (fixed-max exp2) + P store + PV ----
#pragma unroll
        for (int f = 0; f < 2; f++) {
          const int qi = qw + f * 16 + l16;
#pragma unroll
          for (int kg = 0; kg < 4; kg++) {
            float v0 = s[f][kg][0], v1 = s[f][kg][1], v2 = s[f][kg][2], v3 = s[f][kg][3];
            if (edge) {
              int kvb = kb0 + kg * 16 + quad * 4;
              v0 = (kvb + 0 <= qi) ? v0 : -1e30f;
              v1 = (kvb + 1 <= qi) ? v1 : -1e30f;
              v2 = (kvb + 2 <= qi) ? v2 : -1e30f;
              v3 = (kvb + 3 <= qi) ? v3 : -1e30f;
            }
            float e0 = __builtin_amdgcn_exp2f(v0);
            float e1 = __builtin_amdgcn_exp2f(v1);
            float e2 = __builtin_amdgcn_exp2f(v2);
            float e3 = __builtin_amdgcn_exp2f(v3);
            l_p[f] += (e0 + e1) + (e2 + e3);
            uint2 pk;
            pk.x = pack2(e0, e1);
            pk.y = pack2(e2, e3);
            // P[q=l16][kv]: 16B blk = kg*2+(quad>>1), swizzled; 8B half = quad&1
            *(uint2*)&Pl[wave][l16][((kg * 2 + (quad >> 1)) ^ swz) * 8 + (quad & 1) * 4] = pk;
          }
          __threadfence_block();                // same-wave DS write->read order
#pragma unroll
          for (int c = 0; c < 2; c++) {
            bf16x8 pa = *(const bf16x8*)&Pl[wave][l16][((c * 4 + quad) ^ swz) * 8];
#pragma unroll
            for (int g = 0; g < 4; g++) {
              bf16x8 vr = *(const bf16x8*)&Vs[hh][g * 16 + l16][((c * 4 + quad) ^ swz) * 8];
              o[f][g] = __builtin_amdgcn_mfma_f32_16x16x32_bf16(vr, pa, o[f][g], 0, 0, 0);
            }
          }
        }
      }
    }
    __syncthreads();
  }

  // epilogue: reduce l across quads, scale, vectorized store
#pragma unroll
  for (int f = 0; f < 2; f++) {
    float l = l_p[f];
    l += __shfl_xor(l, 16);
    l += __shfl_xor(l, 32);
    float inv_l = 1.0f / l;
    int trow = qw + f * 16 + l16;
#pragma unroll
    for (int g = 0; g < 4; g++) {
      ushort4 st;
      st.x = f2bf(o[f][g][0] * inv_l);
      st.y = f2bf(o[f][g][1] * inv_l);
      st.z = f2bf(o[f][g][2] * inv_l);
      st.w = f2bf(o[f][g][3] * inv_l);
      *(ushort4*)(attn_out + ((size_t)(b * TT + trow)) * CC + h * DD + g * 16 + quad * 4) = st;
    }
  }
}

extern "C" void kernel_launch(void* const* d_in, const int* in_sizes, int n_in,
                              void* d_out, int out_size, void* d_ws, size_t ws_size,
                              hipStream_t stream) {
  const float* x = (const float*)d_in[0];
  const float* w_qkv = (const float*)d_in[1];
  const float* b_qkv = (const float*)d_in[2];
  const float* w_proj = (const float*)d_in[3];
  const float* b_proj = (const float*)d_in[4];
  float* out = (float*)d_out;
  char* ws = (char*)d_ws;

  // workspace layout (72 MB total); xb aliases ao (xb dead before attn runs)
  u16* wqkvT = (u16*)(ws);                    // 3072*1024*2 = 6291456
  u16* wprojT = (u16*)(ws + 6291456);         // 1024*1024*2 = 2097152
  u16* qb = (u16*)(ws + 8388608);             // [B,H,T,D] bf16, 16 MB
  u16* kb = (u16*)(ws + 25165824);            // [B,H,T,D] bf16, 16 MB
  u16* vt = (u16*)(ws + 41943040);            // [B,H,D,T] bf16, 16 MB
  u16* ao = (u16*)(ws + 58720256);            // [B,T,C]   bf16, 16 MB
  u16* xb = ao;                               // x cast to bf16 (aliased)

  cast_f32_bf16<<<dim3(8192), 256, 0, stream>>>(x, xb);
  transpose_cast<<<dim3(96, 32), 256, 0, stream>>>(w_qkv, wqkvT, 1024, 3072);
  transpose_cast<<<dim3(32, 32), 256, 0, stream>>>(w_proj, wprojT, 1024, 1024);
  gemm_bt<<<dim3(64, 24), 256, 0, stream>>>(xb, wqkvT, b_qkv, 8192, 3072, 1024, 0,
                                            qb, kb, vt, nullptr);
  attn_kernel<<<dim3(64, 16), 256, 0, stream>>>(qb, kb, vt, ao);
  gemm_bt<<<dim3(64, 8), 256, 0, stream>>>(ao, wprojT, b_proj, 8192, 1024, 1024, 1,
                                           nullptr, nullptr, nullptr, out);
}